// Round 5
// baseline (475.728 us; speedup 1.0000x reference)
//
#include <hip/hip_runtime.h>

// N=50000, E=600000, IN_CH=128, EDGE_DIM=64, OUT_CH=128
// edge_index delivered as int32.
//
// R11: remove the two structural memory-system sinks found in R10's post-mortem.
//   1) msg_stream writes msgl SEQUENTIALLY (no pos scatter). The permutation
//      moved to segsum's read side: rec64[p] = {src|dstl<<16, orig_e}; segsum
//      gathers msgl[orig_e] rows (random 256B READS out of L3-resident msgl)
//      instead of msg_stream doing random 128B WRITES that drain to HBM.
//   2) hist/binpos: global-atomic versions, no 100KB LDS, 2344 blocks ->
//      all 256 CUs busy (R10 ran 37 blocks = 37 CUs). 600k atomics over 25k
//      addresses (~24-way contention) is trivial for L2-side atomics.
//      Within-bucket order becomes nondeterministic (FP-sum order wobble only).

#define NB 25000
#define NB_SHIFT 1
#define TPW 4   // tiles per wave in msg_stream

typedef __bf16 bf16x8 __attribute__((ext_vector_type(8)));
typedef float  f32x4  __attribute__((ext_vector_type(4)));
typedef unsigned short ushort_t;
typedef unsigned int   uint_t;

__device__ __forceinline__ ushort_t f2b(float f) {   // RNE f32->bf16
    uint_t u = __float_as_uint(f);
    u += 0x7FFF + ((u >> 16) & 1);
    return (ushort_t)(u >> 16);
}
__device__ __forceinline__ uint_t pack2(float a, float b) {
    return (uint_t)f2b(a) | ((uint_t)f2b(b) << 16);
}

// ---------------------------------------------------------------------------
// K1: fold weights -> bf16 k-major tables + f32 bias.
// ---------------------------------------------------------------------------
__global__ void fuse_weights_kernel(const float* __restrict__ Wx,
                                    const float* __restrict__ bx,
                                    const float* __restrict__ We,
                                    const float* __restrict__ be,
                                    const float* __restrict__ Wm,
                                    const float* __restrict__ bm,
                                    ushort_t* __restrict__ WxmT16,
                                    ushort_t* __restrict__ WemT16,
                                    float* __restrict__ bf) {
    int idx = blockIdx.x * blockDim.x + threadIdx.x;
    if (idx < 128 * 128) {
        int r = idx >> 7, c = idx & 127;       // r=k, c=ch
        float acc = 0.f;
        #pragma unroll 8
        for (int j = 0; j < 128; ++j) acc += Wx[r * 128 + j] * Wm[j * 128 + c];
        WxmT16[c * 128 + r] = f2b(acc);
    } else if (idx < 128 * 128 + 64 * 128) {
        int t = idx - 128 * 128;
        int r = t >> 7, c = t & 127;           // r=k(<64), c=ch
        float acc = 0.f;
        #pragma unroll 8
        for (int j = 0; j < 128; ++j) acc += We[r * 128 + j] * Wm[(128 + j) * 128 + c];
        WemT16[c * 64 + r] = f2b(acc);
    } else if (idx < 128 * 128 + 64 * 128 + 128) {
        int c = idx - (128 * 128 + 64 * 128);
        float acc = bm[c];
        #pragma unroll 8
        for (int j = 0; j < 128; ++j)
            acc += bx[j] * Wm[j * 128 + c] + be[j] * Wm[(128 + j) * 128 + c];
        bf[c] = acc;
    }
}

// ---------------------------------------------------------------------------
// K3: ub = bf16(x @ WxmT16 + bf). Operand-swapped MFMA: C[ch, node] so each
// lane holds 4 consecutive channels of node l15 -> packed uint2 stores.
// ---------------------------------------------------------------------------
__global__ __launch_bounds__(256) void node_gemm_kernel(
        const float* __restrict__ x, const ushort_t* __restrict__ WxmT16,
        const float* __restrict__ bf, ushort_t* __restrict__ ub, int N) {
    int tid = threadIdx.x;
    int g = blockIdx.x * 4 + (tid >> 6);
    if (g >= (N / 16) * 2) return;
    int lane = tid & 63, l15 = lane & 15, quad = lane >> 4;
    int n0 = (g >> 1) * 16;
    int chBase = (g & 1) * 64;

    bf16x8 B[4][4];
    #pragma unroll
    for (int ct = 0; ct < 4; ++ct)
        #pragma unroll
        for (int kk = 0; kk < 4; ++kk)
            B[ct][kk] = __builtin_bit_cast(bf16x8, *((const uint4*)
                &WxmT16[(size_t)(chBase + ct * 16 + l15) * 128 + kk * 32 + quad * 8]));

    bf16x8 A[4];
    #pragma unroll
    for (int kk = 0; kk < 4; ++kk) {
        const float4* s = (const float4*)&x[(size_t)(n0 + l15) * 128 + kk * 32 + quad * 8];
        float4 v0 = s[0], v1 = s[1];
        uint4 w;
        w.x = pack2(v0.x, v0.y);
        w.y = pack2(v0.z, v0.w);
        w.z = pack2(v1.x, v1.y);
        w.w = pack2(v1.z, v1.w);
        A[kk] = __builtin_bit_cast(bf16x8, w);
    }

    f32x4 acc[4] = {{0.f,0.f,0.f,0.f},{0.f,0.f,0.f,0.f},
                    {0.f,0.f,0.f,0.f},{0.f,0.f,0.f,0.f}};
    #pragma unroll
    for (int kk = 0; kk < 4; ++kk)
        #pragma unroll
        for (int ct = 0; ct < 4; ++ct)   // SWAPPED: A=weight, B=node rows
            acc[ct] = __builtin_amdgcn_mfma_f32_16x16x32_bf16(B[ct][kk], A[kk], acc[ct], 0, 0, 0);

    #pragma unroll
    for (int ct = 0; ct < 4; ++ct) {
        int ch = chBase + ct * 16 + quad * 4;
        float4 bv = *(const float4*)&bf[ch];
        uint2 w;
        w.x = pack2(acc[ct][0] + bv.x, acc[ct][1] + bv.y);
        w.y = pack2(acc[ct][2] + bv.z, acc[ct][3] + bv.w);
        *((uint2*)&ub[(size_t)(n0 + l15) * 128 + ch]) = w;
    }
}

// ---------------------------------------------------------------------------
// K4: global-atomic histogram of dst buckets. No LDS, full occupancy.
// ---------------------------------------------------------------------------
__global__ __launch_bounds__(256) void hist_kernel(
        const int* __restrict__ ei, int* __restrict__ cnt, int E) {
    int e = blockIdx.x * 256 + threadIdx.x;
    if (e < E) atomicAdd(&cnt[ei[E + e] >> NB_SHIFT], 1);
}

// ---------------------------------------------------------------------------
// K5: exclusive scan of cnt -> start, cur. Single block, 25 elems/thread.
// ---------------------------------------------------------------------------
__global__ __launch_bounds__(1024) void scan_kernel(
        const int* __restrict__ cnt, int* __restrict__ start,
        int* __restrict__ cur, int nb, int E) {
    __shared__ int tot[1024];
    int t = threadIdx.x;
    int v[25]; int sum = 0;
    #pragma unroll
    for (int j = 0; j < 25; ++j) {
        int i = t * 25 + j;
        v[j] = (i < nb) ? cnt[i] : 0;
        sum += v[j];
    }
    tot[t] = sum;
    __syncthreads();
    for (int d = 1; d < 1024; d <<= 1) {
        int val = tot[t];
        int add = (t >= d) ? tot[t - d] : 0;
        __syncthreads();
        tot[t] = val + add;
        __syncthreads();
    }
    int ex = (t == 0) ? 0 : tot[t - 1];
    #pragma unroll
    for (int j = 0; j < 25; ++j) {
        int i = t * 25 + j;
        if (i < nb) { start[i] = ex; cur[i] = ex; }
        ex += v[j];
    }
    if (t == 1023) start[nb] = ex;   // == E
}

// ---------------------------------------------------------------------------
// K6: global-atomic rank-and-place. rec64[p] = {src | dstl<<16, orig_e}.
// One 8B scattered write per edge; within-bucket order nondeterministic.
// ---------------------------------------------------------------------------
__global__ __launch_bounds__(256) void binpos_kernel(
        const int* __restrict__ ei, int* __restrict__ cur,
        uint2* __restrict__ rec64, int E) {
    int e = blockIdx.x * 256 + threadIdx.x;
    if (e >= E) return;
    int d = ei[E + e];
    int b = d >> NB_SHIFT;
    int p = atomicAdd(&cur[b], 1);
    uint_t src  = (uint_t)ei[e];                       // < 65536
    uint_t dstl = (uint_t)(d & ((1 << NB_SHIFT) - 1));
    uint2 r;
    r.x = src | (dstl << 16);
    r.y = (uint_t)e;
    rec64[p] = r;
}

// ---------------------------------------------------------------------------
// K8a: PURE streaming edge GEMM: msgl[e] = bf16(ea[e] @ WemT16), SEQUENTIAL
// write (no pos). Operand-swapped MFMA -> lane holds 4 consecutive channels
// of edge l15 -> packed uint2 stores. Straight-line fast path.
// ---------------------------------------------------------------------------
__global__ __launch_bounds__(256) void msg_stream_kernel(
        const float* __restrict__ ea,
        const ushort_t* __restrict__ WemT16, ushort_t* __restrict__ msgl, int E) {
    int tid = threadIdx.x;
    int g = blockIdx.x * 4 + (tid >> 6);     // global wave id
    int grp = g >> 1;
    int chBase = (g & 1) << 6;
    int t0 = grp * (TPW * 16);
    if (t0 >= E) return;
    int lane = tid & 63, l15 = lane & 15, quad = lane >> 4;

    bf16x8 B[4][2];
    #pragma unroll
    for (int ct = 0; ct < 4; ++ct)
        #pragma unroll
        for (int kk = 0; kk < 2; ++kk)
            B[ct][kk] = __builtin_bit_cast(bf16x8, *((const uint4*)
                &WemT16[(size_t)(chBase + ct * 16 + l15) * 64 + kk * 32 + quad * 8]));

    if (t0 + TPW * 16 <= E) {
        // ---- fast path: all tiles valid; loads all issue up front ----
        bf16x8 a0[TPW], a1[TPW];
        #pragma unroll
        for (int tt = 0; tt < TPW; ++tt) {
            int t16 = t0 + tt * 16;
            const float* rowp = &ea[(size_t)(t16 + l15) * 64];
            const float4* sA = (const float4*)(rowp + quad * 8);
            float4 v0 = sA[0], v1 = sA[1];
            uint4 w0;
            w0.x = pack2(v0.x, v0.y);
            w0.y = pack2(v0.z, v0.w);
            w0.z = pack2(v1.x, v1.y);
            w0.w = pack2(v1.z, v1.w);
            a0[tt] = __builtin_bit_cast(bf16x8, w0);
            const float4* sB = (const float4*)(rowp + 32 + quad * 8);
            float4 v2 = sB[0], v3 = sB[1];
            uint4 w1;
            w1.x = pack2(v2.x, v2.y);
            w1.y = pack2(v2.z, v2.w);
            w1.z = pack2(v3.x, v3.y);
            w1.w = pack2(v3.z, v3.w);
            a1[tt] = __builtin_bit_cast(bf16x8, w1);
        }
        #pragma unroll
        for (int tt = 0; tt < TPW; ++tt) {
            int t16 = t0 + tt * 16;
            f32x4 acc[4] = {{0.f,0.f,0.f,0.f},{0.f,0.f,0.f,0.f},
                            {0.f,0.f,0.f,0.f},{0.f,0.f,0.f,0.f}};
            #pragma unroll
            for (int ct = 0; ct < 4; ++ct)   // SWAPPED operands
                acc[ct] = __builtin_amdgcn_mfma_f32_16x16x32_bf16(B[ct][0], a0[tt], acc[ct], 0, 0, 0);
            #pragma unroll
            for (int ct = 0; ct < 4; ++ct)
                acc[ct] = __builtin_amdgcn_mfma_f32_16x16x32_bf16(B[ct][1], a1[tt], acc[ct], 0, 0, 0);
            #pragma unroll
            for (int ct = 0; ct < 4; ++ct) {
                uint2 w;
                w.x = pack2(acc[ct][0], acc[ct][1]);
                w.y = pack2(acc[ct][2], acc[ct][3]);
                *((uint2*)&msgl[(size_t)(t16 + l15) * 128 + chBase + ct * 16 + quad * 4]) = w;
            }
        }
    } else {
        // ---- tail path (unused when E % (TPW*16) == 0) ----
        for (int tt = 0; tt < TPW; ++tt) {
            int t16 = t0 + tt * 16;
            if (t16 >= E) break;
            const float* rowp = &ea[(size_t)(t16 + l15) * 64];
            const float4* sA = (const float4*)(rowp + quad * 8);
            float4 v0 = sA[0], v1 = sA[1];
            uint4 w0;
            w0.x = pack2(v0.x, v0.y);
            w0.y = pack2(v0.z, v0.w);
            w0.z = pack2(v1.x, v1.y);
            w0.w = pack2(v1.z, v1.w);
            bf16x8 a0 = __builtin_bit_cast(bf16x8, w0);
            const float4* sB = (const float4*)(rowp + 32 + quad * 8);
            float4 v2 = sB[0], v3 = sB[1];
            uint4 w1;
            w1.x = pack2(v2.x, v2.y);
            w1.y = pack2(v2.z, v2.w);
            w1.z = pack2(v3.x, v3.y);
            w1.w = pack2(v3.z, v3.w);
            bf16x8 a1 = __builtin_bit_cast(bf16x8, w1);

            f32x4 acc[4] = {{0.f,0.f,0.f,0.f},{0.f,0.f,0.f,0.f},
                            {0.f,0.f,0.f,0.f},{0.f,0.f,0.f,0.f}};
            #pragma unroll
            for (int ct = 0; ct < 4; ++ct)
                acc[ct] = __builtin_amdgcn_mfma_f32_16x16x32_bf16(B[ct][0], a0, acc[ct], 0, 0, 0);
            #pragma unroll
            for (int ct = 0; ct < 4; ++ct)
                acc[ct] = __builtin_amdgcn_mfma_f32_16x16x32_bf16(B[ct][1], a1, acc[ct], 0, 0, 0);
            #pragma unroll
            for (int ct = 0; ct < 4; ++ct) {
                uint2 w;
                w.x = pack2(acc[ct][0], acc[ct][1]);
                w.y = pack2(acc[ct][2], acc[ct][3]);
                *((uint2*)&msgl[(size_t)(t16 + l15) * 128 + chBase + ct * 16 + quad * 4]) = w;
            }
        }
    }
}

// ---------------------------------------------------------------------------
// K8b: wave-per-bucket segment sum, register accumulators. 4 edges/iter
// (quarter q), uint4 (16B) loads; msgl rows gathered via rec64[p].y (random
// 256B reads, L3-resident), ub rows via rec64[p].x (L2/L3-resident).
// 2-deep rec prefetch + 1-deep data pipeline. Full-wave shfl reduce.
// ---------------------------------------------------------------------------
__global__ __launch_bounds__(256) void segsum_kernel(
        const ushort_t* __restrict__ msgl, const ushort_t* __restrict__ ub,
        const uint2* __restrict__ rec64, const int* __restrict__ start,
        const float* __restrict__ beta, float* __restrict__ out, int N) {
    int wid = blockIdx.x * 4 + (threadIdx.x >> 6);   // bucket id
    if (wid >= NB) return;
    int lane = threadIdx.x & 63;
    int q = lane >> 4;             // edge slot within iteration (0..3)
    int c16 = lane & 15;           // channel group: ch 8*c16 .. 8*c16+7

    int s0 = start[wid], s1 = start[wid + 1];
    float a0[8] = {0.f,0.f,0.f,0.f,0.f,0.f,0.f,0.f};
    float a1[8] = {0.f,0.f,0.f,0.f,0.f,0.f,0.f,0.f};

    uint2 zero; zero.x = 0u; zero.y = 0u;
    int pA = s0 + q;
    uint2 rA = (pA < s1) ? rec64[pA] : zero;
    int pB = pA + 4;
    uint2 rB = (pB < s1) ? rec64[pB] : zero;

    uint4 mvA = *(const uint4*)&msgl[(size_t)rA.y * 128 + (c16 << 3)];
    uint4 uvA = *(const uint4*)&ub[(size_t)(rA.x & 0xFFFFu) * 128 + (c16 << 3)];

    while (pA < s1) {
        // prefetch rec two iterations ahead; issue next iteration's data
        int pC = pB + 4;
        uint2 rC = (pC < s1) ? rec64[pC] : zero;
        uint4 mvB = *(const uint4*)&msgl[(size_t)rB.y * 128 + (c16 << 3)];
        uint4 uvB = *(const uint4*)&ub[(size_t)(rB.x & 0xFFFFu) * 128 + (c16 << 3)];

        float w1 = (rA.x >> 16) ? 1.f : 0.f;
        float w0 = 1.f - w1;
        {
            float mlo, mhi;
            mlo = __uint_as_float(mvA.x << 16)         + __uint_as_float(uvA.x << 16);
            mhi = __uint_as_float(mvA.x & 0xFFFF0000u) + __uint_as_float(uvA.x & 0xFFFF0000u);
            mlo = fmaxf(mlo, 0.01f * mlo); mhi = fmaxf(mhi, 0.01f * mhi);
            a0[0] += mlo * w0; a1[0] += mlo * w1;
            a0[1] += mhi * w0; a1[1] += mhi * w1;
            mlo = __uint_as_float(mvA.y << 16)         + __uint_as_float(uvA.y << 16);
            mhi = __uint_as_float(mvA.y & 0xFFFF0000u) + __uint_as_float(uvA.y & 0xFFFF0000u);
            mlo = fmaxf(mlo, 0.01f * mlo); mhi = fmaxf(mhi, 0.01f * mhi);
            a0[2] += mlo * w0; a1[2] += mlo * w1;
            a0[3] += mhi * w0; a1[3] += mhi * w1;
            mlo = __uint_as_float(mvA.z << 16)         + __uint_as_float(uvA.z << 16);
            mhi = __uint_as_float(mvA.z & 0xFFFF0000u) + __uint_as_float(uvA.z & 0xFFFF0000u);
            mlo = fmaxf(mlo, 0.01f * mlo); mhi = fmaxf(mhi, 0.01f * mhi);
            a0[4] += mlo * w0; a1[4] += mlo * w1;
            a0[5] += mhi * w0; a1[5] += mhi * w1;
            mlo = __uint_as_float(mvA.w << 16)         + __uint_as_float(uvA.w << 16);
            mhi = __uint_as_float(mvA.w & 0xFFFF0000u) + __uint_as_float(uvA.w & 0xFFFF0000u);
            mlo = fmaxf(mlo, 0.01f * mlo); mhi = fmaxf(mhi, 0.01f * mhi);
            a0[6] += mlo * w0; a1[6] += mlo * w1;
            a0[7] += mhi * w0; a1[7] += mhi * w1;
        }

        pA = pB; rA = rB; mvA = mvB; uvA = uvB;
        pB = pC; rB = rC;
    }

    // reduce across the 4 quarters (all lanes end with full sums)
    #pragma unroll
    for (int j = 0; j < 8; ++j) {
        a0[j] += __shfl_xor(a0[j], 16);
        a0[j] += __shfl_xor(a0[j], 32);
        a1[j] += __shfl_xor(a1[j], 16);
        a1[j] += __shfl_xor(a1[j], 32);
    }

    float rb = beta[0];
    rb = rb > 0.f ? rb : 0.f;
    int h   = lane >> 5;           // node half
    int sub = (lane >> 4) & 1;     // which float4 of the 8-ch group
    int n = (wid << 1) + h;
    if (n < N) {
        float x0, x1, x2, x3;
        if (h == 0) {
            if (sub == 0) { x0 = a0[0]; x1 = a0[1]; x2 = a0[2]; x3 = a0[3]; }
            else          { x0 = a0[4]; x1 = a0[5]; x2 = a0[6]; x3 = a0[7]; }
        } else {
            if (sub == 0) { x0 = a1[0]; x1 = a1[1]; x2 = a1[2]; x3 = a1[3]; }
            else          { x0 = a1[4]; x1 = a1[5]; x2 = a1[6]; x3 = a1[7]; }
        }
        float4 v;
        v.x = rb / (1.f + __expf(-x0));
        v.y = rb / (1.f + __expf(-x1));
        v.z = rb / (1.f + __expf(-x2));
        v.w = rb / (1.f + __expf(-x3));
        ((float4*)out)[(size_t)n * 32 + c16 * 2 + sub] = v;
    }
}

// ---------------------------------------------------------------------------
extern "C" void kernel_launch(void* const* d_in, const int* in_sizes, int n_in,
                              void* d_out, int out_size, void* d_ws, size_t ws_size,
                              hipStream_t stream) {
    const float* x    = (const float*)d_in[0];
    const int*   ei   = (const int*)d_in[1];
    const float* ea   = (const float*)d_in[2];
    const float* Wx   = (const float*)d_in[3];
    const float* bx   = (const float*)d_in[4];
    const float* We   = (const float*)d_in[5];
    const float* be   = (const float*)d_in[6];
    const float* Wm   = (const float*)d_in[7];
    const float* bm   = (const float*)d_in[8];
    const float* beta = (const float*)d_in[9];

    int N = in_sizes[0] / 128;   // 50000
    int E = in_sizes[2] / 64;    // 600000

    float* out = (float*)d_out;

    // workspace layout (bytes)
    char* ws = (char*)d_ws;
    ushort_t* WxmT16 = (ushort_t*)(ws);                    // 32768
    ushort_t* WemT16 = (ushort_t*)(ws + 32768);            // 16384
    float*    bf     = (float*)(ws + 49152);               // 512
    ushort_t* ub     = (ushort_t*)(ws + 65536);            // 12.8 MB (bf16)
    size_t off = 65536 + (size_t)N * 128 * 2;
    uint2* rec64   = (uint2*)(ws + off);                   // 4.8 MB
    off += (size_t)E * 8;
    int* cnt       = (int*)(ws + off);                     // 100 KB
    int* startb    = (int*)(ws + off + 131072);            // 100 KB + 4
    int* cur       = (int*)(ws + off + 262144);            // 100 KB
    ushort_t* msgl = (ushort_t*)(ws + off + 393216);       // 153.6 MB (bf16)

    hipMemsetAsync(cnt, 0, (size_t)NB * sizeof(int), stream);

    fuse_weights_kernel<<<(24704 + 255) / 256, 256, 0, stream>>>(
        Wx, bx, We, be, Wm, bm, WxmT16, WemT16, bf);

    node_gemm_kernel<<<(N / 16 * 2 + 3) / 4, 256, 0, stream>>>(
        x, WxmT16, bf, ub, N);

    int ebBlocks = (E + 255) / 256;   // 2344
    hist_kernel<<<ebBlocks, 256, 0, stream>>>(ei, cnt, E);
    scan_kernel<<<1, 1024, 0, stream>>>(cnt, startb, cur, NB, E);
    binpos_kernel<<<ebBlocks, 256, 0, stream>>>(ei, cur, rec64, E);

    int ntile  = (E + 15) / 16;                    // 37500
    int ngrp   = (ntile + TPW - 1) / TPW;          // 9375
    int nwaves = ngrp * 2;                         // 18750
    msg_stream_kernel<<<(nwaves + 3) / 4, 256, 0, stream>>>(
        ea, WemT16, msgl, E);

    segsum_kernel<<<(NB + 3) / 4, 256, 0, stream>>>(
        msgl, ub, rec64, startb, beta, out, N);
}